// Round 9
// baseline (248.198 us; speedup 1.0000x reference)
//
#include <hip/hip_runtime.h>
#include <hip/hip_bf16.h>

typedef unsigned short u16;
typedef __attribute__((ext_vector_type(8))) short bf16x8;
typedef __attribute__((ext_vector_type(4))) float f32x4;

#define SEQ_L 4096
#define M_TOT 16384   // B*L

__device__ __forceinline__ float bf2f(u16 x) {
    unsigned u = ((unsigned)x) << 16;
    return __builtin_bit_cast(float, u);
}
__device__ __forceinline__ u16 f2bf(float f) {
    unsigned u = __builtin_bit_cast(unsigned, f);
    u += 0x7FFFu + ((u >> 16) & 1u);   // round-to-nearest-even
    return (u16)(u >> 16);
}
// async 16B global->LDS (direct-to-LDS DMA; LDS dest = wave-uniform base + lane*16)
__device__ __forceinline__ void gload16(const u16* g, u16* l) {
    __builtin_amdgcn_global_load_lds(
        (const __attribute__((address_space(1))) unsigned int*)g,
        (__attribute__((address_space(3))) unsigned int*)l, 16, 0, 0);
}

// ---- prep_all: pack six fp32 inputs -> x bf16 | Wqkv,Wout -> bf16 | mask compact ----
__global__ __launch_bounds__(256) void prep_all(
    const float* __restrict__ in0, const float* __restrict__ in1, const float* __restrict__ in2,
    const float* __restrict__ in3, const float* __restrict__ in4, const float* __restrict__ in5,
    const float* __restrict__ Wqkv, const float* __restrict__ Wout, const void* __restrict__ mask,
    u16* __restrict__ x, u16* __restrict__ Wqkv_bf, u16* __restrict__ Wout_bf,
    unsigned char* __restrict__ cmask) {
    int id = blockIdx.x * 256 + threadIdx.x;
    if (id < 1572864) {
        const float* ins[6] = {in0, in1, in2, in3, in4, in5};
        int which = id >> 18, j = id & 262143;
        int m = j >> 4, c8 = j & 15;
        const float* sp = ins[which] + (size_t)m * 128 + c8 * 8;
        float4 a = *(const float4*)sp;
        float4 b = *(const float4*)(sp + 4);
        u16 t[8] = {f2bf(a.x), f2bf(a.y), f2bf(a.z), f2bf(a.w),
                    f2bf(b.x), f2bf(b.y), f2bf(b.z), f2bf(b.w)};
        *(uint4*)(x + (size_t)m * 768 + which * 128 + c8 * 8) = *(uint4*)t;
    } else if (id < 1572864 + 73728 + 8192) {
        int i = id - 1572864;
        const float* src = (i < 73728) ? Wqkv : Wout;
        u16* dst = (i < 73728) ? Wqkv_bf : Wout_bf;
        if (i >= 73728) i -= 73728;
        const float* sp = src + (size_t)i * 8;
        float4 a = *(const float4*)sp;
        float4 b = *(const float4*)(sp + 4);
        u16 t[8] = {f2bf(a.x), f2bf(a.y), f2bf(a.z), f2bf(a.w),
                    f2bf(b.x), f2bf(b.y), f2bf(b.z), f2bf(b.w)};
        *(uint4*)(dst + (size_t)i * 8) = *(uint4*)t;
    } else if (id < 1572864 + 73728 + 8192 + 4096) {
        int i = id - 1572864 - 73728 - 8192;
        int bi = i >> 6, bj = i & 63;
        size_t e = (size_t)(bi * 64) * SEQ_L + (size_t)bj * 64;
        const unsigned char* p8 = (const unsigned char*)mask;
        unsigned w0 = *(const unsigned*)mask;   // [0][0],[0][1] always true -> fingerprint
        bool v;
        if (w0 == 0x01010101u || w0 == 0xFFFFFFFFu)      v = p8[e] != 0;
        else if (w0 == 0x3F803F80u || w0 == 0x3C003C00u) v = ((const u16*)mask)[e] != 0;
        else                                             v = ((const unsigned*)mask)[e] != 0;
        cmask[i] = v ? 1 : 0;
    }
}

// ---------------- QKV GEMM, 128x64 tile (grid 1536) ----------------
__global__ __launch_bounds__(256, 4) void qkv_gemm(
    const u16* __restrict__ X, const u16* __restrict__ W, const float* __restrict__ bias,
    u16* __restrict__ qk, u16* __restrict__ vt) {
    __shared__ __align__(16) u16 As[128 * 64];
    __shared__ __align__(16) u16 Bs[64 * 64];
    int m0 = blockIdx.x * 128, n0 = blockIdx.y * 64;
    int tid = threadIdx.x, lane = tid & 63, w = tid >> 6;
    int ln = lane & 15, quad = lane >> 4;
    int rw = (w >> 1) * 64, cw = (w & 1) * 32;
    int lr8 = lane >> 3, lc = lane & 7;
    f32x4 acc[4][2] = {};
    for (int kk = 0; kk < 768; kk += 64) {
        __syncthreads();
        #pragma unroll
        for (int j = 0; j < 4; j++) {
            int r0 = w * 32 + j * 8, r = r0 + lr8;
            gload16(X + (size_t)(m0 + r) * 768 + kk + ((lc ^ (r & 7)) * 8), As + r0 * 64 + lane * 8);
        }
        #pragma unroll
        for (int j = 0; j < 2; j++) {
            int r0 = w * 16 + j * 8, r = r0 + lr8;
            gload16(W + (size_t)(n0 + r) * 768 + kk + ((lc ^ (r & 7)) * 8), Bs + r0 * 64 + lane * 8);
        }
        __syncthreads();
        #pragma unroll
        for (int s = 0; s < 2; s++) {
            bf16x8 af[4], bfr[2];
            #pragma unroll
            for (int i = 0; i < 4; i++) {
                int R = rw + i * 16 + ln;
                af[i] = *(const bf16x8*)(As + R * 64 + ((4 * s + quad) ^ (ln & 7)) * 8);
            }
            #pragma unroll
            for (int t = 0; t < 2; t++) {
                int R = cw + t * 16 + ln;
                bfr[t] = *(const bf16x8*)(Bs + R * 64 + ((4 * s + quad) ^ (ln & 7)) * 8);
            }
            #pragma unroll
            for (int i = 0; i < 4; i++)
                #pragma unroll
                for (int t = 0; t < 2; t++)
                    acc[i][t] = __builtin_amdgcn_mfma_f32_16x16x32_bf16(af[i], bfr[t], acc[i][t], 0, 0, 0);
        }
    }
    #pragma unroll
    for (int i = 0; i < 4; i++) {
        int row0 = m0 + rw + i * 16 + 4 * quad;
        #pragma unroll
        for (int t = 0; t < 2; t++) {
            int col = n0 + cw + t * 16 + ln;
            float bv = bias[col];
            if (col < 512) {   // block-uniform (n0 is 64-aligned)
                #pragma unroll
                for (int r = 0; r < 4; r++)
                    qk[(size_t)(row0 + r) * 512 + col] = f2bf(acc[i][t][r] + bv);
            } else {
                int d = col - 512;
                int b = row0 >> 12, seq = row0 & 4095;
                u16 pk[4] = {f2bf(acc[i][t][0] + bv), f2bf(acc[i][t][1] + bv),
                             f2bf(acc[i][t][2] + bv), f2bf(acc[i][t][3] + bv)};
                *(ushort4*)(vt + ((size_t)(b * 2 + (d >> 7)) * 128 + (d & 127)) * SEQ_L + seq)
                    = *(ushort4*)pk;
            }
        }
    }
}

// ---- fused attention + out-proj: register-resident K/V fragments, barrier-free loop ----
// One block per (b, q-block, 32-row half); waves 0-1 = channel 0, 2-3 = channel 1.
// K frags prefetched 1 iter ahead into regs (reuse after S reads them); V frags
// reloaded after PV. No LDS in the hot loop except wave-private Ps.
__global__ __launch_bounds__(256, 2) void attn_out(
    const u16* __restrict__ qk, const u16* __restrict__ vt, const u16* __restrict__ Wout,
    const unsigned char* __restrict__ cmask, const float* __restrict__ bout,
    float* __restrict__ out) {
    // loop phase: Ps = 4 waves x 16x72 u16 (wave-private). phase B overlay:
    // Ao[32][264] (8448 u16) + Bs[256][64] (16384 u16) = 24832 u16 = 49.7 KB.
    __shared__ __align__(16) u16 smem[24832];

    int idx = blockIdx.x;
    int qi = 63 - (idx >> 3);          // heavy q-rows first
    int b = (idx >> 1) & 3, half = idx & 1;
    int tid = threadIdx.x, lane = tid & 63, w = tid >> 6;
    int ln = lane & 15, quad = lane >> 4;
    int cw = w >> 1, wr = w & 1;       // channel, 16-row tile within the 32-row half
    const float scale = 0.08838834764831845f;  // 1/sqrt(128)

    const unsigned char* mrow = cmask + qi * 64;
    unsigned long long bm = 0;
    for (int k = 0; k <= qi; k++) bm |= (unsigned long long)(mrow[k] != 0) << k;

    const u16* kB = qk + (size_t)b * SEQ_L * 512 + 256 + cw * 128;
    const u16* vB = vt + (size_t)(b * 2 + cw) * 128 * SEQ_L;

    // Q fragments: A[m=ln][k=32s+8*quad+j]
    bf16x8 qf[4];
    {
        size_t grow = (size_t)(b * SEQ_L + qi * 64 + half * 32 + wr * 16 + ln);
        const u16* qp = qk + grow * 512 + cw * 128;
        #pragma unroll
        for (int s = 0; s < 4; s++) qf[s] = *(const bf16x8*)(qp + 32 * s + 8 * quad);
    }
    float m_st[4], l_st[4];
    #pragma unroll
    for (int r = 0; r < 4; r++) { m_st[r] = -1e30f; l_st[r] = 0.f; }
    f32x4 accO[8] = {};
    u16* Ps = smem + w * 1152;   // wave-private 16x72

    bf16x8 kf[4][4];   // B-frags of K: kf[t][s] = K[t*16+ln][32s+8q..]
    bf16x8 vf[8][2];   // B-frags of V^T: vf[nt][s2] = Vt[nt*16+ln][32s2+8q..]
    int cur = __ffsll(bm) - 1; bm &= bm - 1;   // diagonal guarantees >=1
    {
        const u16* kp = kB + (size_t)cur * 64 * 512;
        #pragma unroll
        for (int t = 0; t < 4; t++)
            #pragma unroll
            for (int s = 0; s < 4; s++)
                kf[t][s] = *(const bf16x8*)(kp + (size_t)(t * 16 + ln) * 512 + 32 * s + 8 * quad);
        const u16* vp = vB + cur * 64;
        #pragma unroll
        for (int nt = 0; nt < 8; nt++)
            #pragma unroll
            for (int s2 = 0; s2 < 2; s2++)
                vf[nt][s2] = *(const bf16x8*)(vp + (size_t)(nt * 16 + ln) * SEQ_L + 32 * s2 + 8 * quad);
    }
    while (cur >= 0) {
        // S = Q K^T : D[m=4*quad+r][n=ln+16t]
        f32x4 accS[4] = {};
        #pragma unroll
        for (int s = 0; s < 4; s++)
            #pragma unroll
            for (int t = 0; t < 4; t++)
                accS[t] = __builtin_amdgcn_mfma_f32_16x16x32_bf16(qf[s], kf[t][s], accS[t], 0, 0, 0);

        int nxt = -1;
        if (bm) { nxt = __ffsll(bm) - 1; bm &= bm - 1; }
        if (nxt >= 0) {   // prefetch next K into kf (S already read them)
            const u16* kp = kB + (size_t)nxt * 64 * 512;
            #pragma unroll
            for (int t = 0; t < 4; t++)
                #pragma unroll
                for (int s = 0; s < 4; s++)
                    kf[t][s] = *(const bf16x8*)(kp + (size_t)(t * 16 + ln) * 512 + 32 * s + 8 * quad);
        }

        // online softmax per row m = 4*quad + r; P staged unnormalized into Ps
        #pragma unroll
        for (int r = 0; r < 4; r++) {
            float sv[4];
            float mx = -1e30f;
            #pragma unroll
            for (int t = 0; t < 4; t++) { sv[t] = accS[t][r] * scale; mx = fmaxf(mx, sv[t]); }
            #pragma unroll
            for (int off = 1; off < 16; off <<= 1) mx = fmaxf(mx, __shfl_xor(mx, off, 64));
            float nm = fmaxf(m_st[r], mx);
            float alpha = __expf(m_st[r] - nm);
            m_st[r] = nm;
            float rs = 0.f;
            #pragma unroll
            for (int t = 0; t < 4; t++) {
                float p = __expf(sv[t] - nm);
                Ps[(4 * quad + r) * 72 + ln + 16 * t] = f2bf(p);
                rs += p;
            }
            #pragma unroll
            for (int off = 1; off < 16; off <<= 1) rs += __shfl_xor(rs, off, 64);
            l_st[r] = l_st[r] * alpha + rs;
            #pragma unroll
            for (int nt = 0; nt < 8; nt++) accO[nt][r] *= alpha;
        }
        // O += P V  (pf from wave-private LDS; vf from registers)
        #pragma unroll
        for (int s2 = 0; s2 < 2; s2++) {
            bf16x8 pf = *(const bf16x8*)(Ps + ln * 72 + 32 * s2 + 8 * quad);
            #pragma unroll
            for (int nt = 0; nt < 8; nt++)
                accO[nt] = __builtin_amdgcn_mfma_f32_16x16x32_bf16(pf, vf[nt][s2], accO[nt], 0, 0, 0);
        }
        if (nxt >= 0) {   // reload V for next (PV already read current)
            const u16* vp = vB + nxt * 64;
            #pragma unroll
            for (int nt = 0; nt < 8; nt++)
                #pragma unroll
                for (int s2 = 0; s2 < 2; s2++)
                    vf[nt][s2] = *(const bf16x8*)(vp + (size_t)(nt * 16 + ln) * SEQ_L + 32 * s2 + 8 * quad);
        }
        cur = nxt;
    }

    __syncthreads();   // Ps dead; waves aligned before Ao overlay
    u16* Ao = smem;            // [32][264]
    u16* Bs = smem + 32 * 264; // [256][64]
    {
        float inv[4];
        #pragma unroll
        for (int r = 0; r < 4; r++) inv[r] = 1.0f / fmaxf(l_st[r], 1e-20f);
        #pragma unroll
        for (int nt = 0; nt < 8; nt++)
            #pragma unroll
            for (int r = 0; r < 4; r++)
                Ao[(wr * 16 + 4 * quad + r) * 264 + cw * 128 + nt * 16 + ln]
                    = f2bf(accO[nt][r] * inv[r]);
    }

    // -------- phase B: out[32,256] = Ao @ Wout^T + bias, k streamed in 4 chunks --------
    f32x4 oacc[2][4] = {};
    for (int kk = 0; kk < 4; kk++) {
        __syncthreads();   // Ao visibility (kk=0) / WAR on Bs
        #pragma unroll
        for (int j = 0; j < 8; j++) {
            int o0 = w * 64 + j * 8, o = o0 + (lane >> 3);
            gload16(Wout + (size_t)o * 256 + kk * 64 + (((lane & 7) ^ (o & 7)) * 8),
                    Bs + o0 * 64 + lane * 8);
        }
        __syncthreads();   // drain
        #pragma unroll
        for (int s = 0; s < 2; s++) {
            bf16x8 af[2], bfr[4];
            #pragma unroll
            for (int i = 0; i < 2; i++)
                af[i] = *(const bf16x8*)(Ao + (i * 16 + ln) * 264 + kk * 64 + 32 * s + 8 * quad);
            #pragma unroll
            for (int t = 0; t < 4; t++) {
                int o = w * 64 + t * 16 + ln;
                bfr[t] = *(const bf16x8*)(Bs + o * 64 + ((4 * s + quad) ^ (ln & 7)) * 8);
            }
            #pragma unroll
            for (int i = 0; i < 2; i++)
                #pragma unroll
                for (int t = 0; t < 4; t++)
                    oacc[i][t] = __builtin_amdgcn_mfma_f32_16x16x32_bf16(af[i], bfr[t], oacc[i][t], 0, 0, 0);
        }
    }
    const size_t hlf = (size_t)M_TOT * 128;
    #pragma unroll
    for (int t = 0; t < 4; t++) {
        int o = w * 64 + t * 16 + ln;
        float bv = bout[o];
        float* base = (o < 128) ? (out + o) : (out + hlf + (o - 128));
        #pragma unroll
        for (int i = 0; i < 2; i++) {
            int row = b * SEQ_L + qi * 64 + half * 32 + i * 16 + 4 * quad;
            #pragma unroll
            for (int r = 0; r < 4; r++)
                base[(size_t)(row + r) * 128] = oacc[i][t][r] + bv;
        }
    }
}

extern "C" void kernel_launch(void* const* d_in, const int* in_sizes, int n_in,
                              void* d_out, int out_size, void* d_ws, size_t ws_size,
                              hipStream_t stream) {
    char* ws = (char*)d_ws;
    u16* x_bf    = (u16*)ws;                          // 16384*768  = 25.2 MB
    u16* qk_buf  = x_bf + (size_t)M_TOT * 768;        // 16384*512  = 16.8 MB
    u16* vt_buf  = qk_buf + (size_t)M_TOT * 512;      // 1024*4096  =  8.4 MB
    u16* Wqkv_bf = vt_buf + (size_t)1024 * SEQ_L;     // 589824
    u16* Wout_bf = Wqkv_bf + 589824;                  // 65536
    unsigned char* cmask = (unsigned char*)(Wout_bf + 65536);

    hipLaunchKernelGGL(prep_all, dim3(6480), dim3(256), 0, stream,
                       (const float*)d_in[0], (const float*)d_in[1], (const float*)d_in[2],
                       (const float*)d_in[3], (const float*)d_in[4], (const float*)d_in[5],
                       (const float*)d_in[6], (const float*)d_in[8], d_in[10],
                       x_bf, Wqkv_bf, Wout_bf, cmask);
    hipLaunchKernelGGL(qkv_gemm, dim3(128, 12), dim3(256), 0, stream,
                       x_bf, Wqkv_bf, (const float*)d_in[7], qk_buf, vt_buf);
    hipLaunchKernelGGL(attn_out, dim3(512), dim3(256), 0, stream,
                       qk_buf, vt_buf, Wout_bf, cmask, (const float*)d_in[9], (float*)d_out);
}

// Round 10
// 218.972 us; speedup vs baseline: 1.1335x; 1.1335x over previous
//
#include <hip/hip_runtime.h>
#include <hip/hip_bf16.h>

typedef unsigned short u16;
typedef __attribute__((ext_vector_type(8))) short bf16x8;
typedef __attribute__((ext_vector_type(4))) float f32x4;

#define SEQ_L 4096
#define M_TOT 16384   // B*L

__device__ __forceinline__ float bf2f(u16 x) {
    unsigned u = ((unsigned)x) << 16;
    return __builtin_bit_cast(float, u);
}
__device__ __forceinline__ u16 f2bf(float f) {
    unsigned u = __builtin_bit_cast(unsigned, f);
    u += 0x7FFFu + ((u >> 16) & 1u);   // round-to-nearest-even
    return (u16)(u >> 16);
}
// async 16B global->LDS (direct-to-LDS DMA; LDS dest = wave-uniform base + lane*16)
__device__ __forceinline__ void gload16(const u16* g, u16* l) {
    __builtin_amdgcn_global_load_lds(
        (const __attribute__((address_space(1))) unsigned int*)g,
        (__attribute__((address_space(3))) unsigned int*)l, 16, 0, 0);
}

// ---- prep_all: pack six fp32 inputs -> x bf16 | Wqkv,Wout -> bf16 | mask compact ----
__global__ __launch_bounds__(256) void prep_all(
    const float* __restrict__ in0, const float* __restrict__ in1, const float* __restrict__ in2,
    const float* __restrict__ in3, const float* __restrict__ in4, const float* __restrict__ in5,
    const float* __restrict__ Wqkv, const float* __restrict__ Wout, const void* __restrict__ mask,
    u16* __restrict__ x, u16* __restrict__ Wqkv_bf, u16* __restrict__ Wout_bf,
    unsigned char* __restrict__ cmask) {
    int id = blockIdx.x * 256 + threadIdx.x;
    if (id < 1572864) {
        const float* ins[6] = {in0, in1, in2, in3, in4, in5};
        int which = id >> 18, j = id & 262143;
        int m = j >> 4, c8 = j & 15;
        const float* sp = ins[which] + (size_t)m * 128 + c8 * 8;
        float4 a = *(const float4*)sp;
        float4 b = *(const float4*)(sp + 4);
        u16 t[8] = {f2bf(a.x), f2bf(a.y), f2bf(a.z), f2bf(a.w),
                    f2bf(b.x), f2bf(b.y), f2bf(b.z), f2bf(b.w)};
        *(uint4*)(x + (size_t)m * 768 + which * 128 + c8 * 8) = *(uint4*)t;
    } else if (id < 1572864 + 73728 + 8192) {
        int i = id - 1572864;
        const float* src = (i < 73728) ? Wqkv : Wout;
        u16* dst = (i < 73728) ? Wqkv_bf : Wout_bf;
        if (i >= 73728) i -= 73728;
        const float* sp = src + (size_t)i * 8;
        float4 a = *(const float4*)sp;
        float4 b = *(const float4*)(sp + 4);
        u16 t[8] = {f2bf(a.x), f2bf(a.y), f2bf(a.z), f2bf(a.w),
                    f2bf(b.x), f2bf(b.y), f2bf(b.z), f2bf(b.w)};
        *(uint4*)(dst + (size_t)i * 8) = *(uint4*)t;
    } else if (id < 1572864 + 73728 + 8192 + 4096) {
        int i = id - 1572864 - 73728 - 8192;
        int bi = i >> 6, bj = i & 63;
        size_t e = (size_t)(bi * 64) * SEQ_L + (size_t)bj * 64;
        const unsigned char* p8 = (const unsigned char*)mask;
        unsigned w0 = *(const unsigned*)mask;   // [0][0],[0][1] always true -> fingerprint
        bool v;
        if (w0 == 0x01010101u || w0 == 0xFFFFFFFFu)      v = p8[e] != 0;
        else if (w0 == 0x3F803F80u || w0 == 0x3C003C00u) v = ((const u16*)mask)[e] != 0;
        else                                             v = ((const unsigned*)mask)[e] != 0;
        cmask[i] = v ? 1 : 0;
    }
}

// ---------------- QKV GEMM, 128x64 tile (grid 1536) ----------------
__global__ __launch_bounds__(256, 4) void qkv_gemm(
    const u16* __restrict__ X, const u16* __restrict__ W, const float* __restrict__ bias,
    u16* __restrict__ qk, u16* __restrict__ vt) {
    __shared__ __align__(16) u16 As[128 * 64];
    __shared__ __align__(16) u16 Bs[64 * 64];
    int m0 = blockIdx.x * 128, n0 = blockIdx.y * 64;
    int tid = threadIdx.x, lane = tid & 63, w = tid >> 6;
    int ln = lane & 15, quad = lane >> 4;
    int rw = (w >> 1) * 64, cw = (w & 1) * 32;
    int lr8 = lane >> 3, lc = lane & 7;
    f32x4 acc[4][2] = {};
    for (int kk = 0; kk < 768; kk += 64) {
        __syncthreads();
        #pragma unroll
        for (int j = 0; j < 4; j++) {
            int r0 = w * 32 + j * 8, r = r0 + lr8;
            gload16(X + (size_t)(m0 + r) * 768 + kk + ((lc ^ (r & 7)) * 8), As + r0 * 64 + lane * 8);
        }
        #pragma unroll
        for (int j = 0; j < 2; j++) {
            int r0 = w * 16 + j * 8, r = r0 + lr8;
            gload16(W + (size_t)(n0 + r) * 768 + kk + ((lc ^ (r & 7)) * 8), Bs + r0 * 64 + lane * 8);
        }
        __syncthreads();
        #pragma unroll
        for (int s = 0; s < 2; s++) {
            bf16x8 af[4], bfr[2];
            #pragma unroll
            for (int i = 0; i < 4; i++) {
                int R = rw + i * 16 + ln;
                af[i] = *(const bf16x8*)(As + R * 64 + ((4 * s + quad) ^ (ln & 7)) * 8);
            }
            #pragma unroll
            for (int t = 0; t < 2; t++) {
                int R = cw + t * 16 + ln;
                bfr[t] = *(const bf16x8*)(Bs + R * 64 + ((4 * s + quad) ^ (ln & 7)) * 8);
            }
            #pragma unroll
            for (int i = 0; i < 4; i++)
                #pragma unroll
                for (int t = 0; t < 2; t++)
                    acc[i][t] = __builtin_amdgcn_mfma_f32_16x16x32_bf16(af[i], bfr[t], acc[i][t], 0, 0, 0);
        }
    }
    #pragma unroll
    for (int i = 0; i < 4; i++) {
        int row0 = m0 + rw + i * 16 + 4 * quad;
        #pragma unroll
        for (int t = 0; t < 2; t++) {
            int col = n0 + cw + t * 16 + ln;
            float bv = bias[col];
            if (col < 512) {   // block-uniform (n0 is 64-aligned)
                #pragma unroll
                for (int r = 0; r < 4; r++)
                    qk[(size_t)(row0 + r) * 512 + col] = f2bf(acc[i][t][r] + bv);
            } else {
                int d = col - 512;
                int b = row0 >> 12, seq = row0 & 4095;
                u16 pk[4] = {f2bf(acc[i][t][0] + bv), f2bf(acc[i][t][1] + bv),
                             f2bf(acc[i][t][2] + bv), f2bf(acc[i][t][3] + bv)};
                *(ushort4*)(vt + ((size_t)(b * 2 + (d >> 7)) * 128 + (d & 127)) * SEQ_L + seq)
                    = *(ushort4*)pk;
            }
        }
    }
}

// ---- fused attention + out-proj: one block per (b, q-block, 32-row half) ----
// 4 waves: waves 0-1 = channel 0, waves 2-3 = channel 1, channels in parallel.
// LDS exactly 80 KiB -> 2 blocks/CU. Complementary qi pairing: idx and idx+256
// land on the same CU under round-robin dispatch, so qi(idx)+qi(idx+256)=63 ->
// every CU's expected iteration load is constant (kills the r8 systematic skew).
__global__ __launch_bounds__(256) void attn_out(
    const u16* __restrict__ qk, const u16* __restrict__ vt, const u16* __restrict__ Wout,
    const unsigned char* __restrict__ cmask, const float* __restrict__ bout,
    float* __restrict__ out) {
    __shared__ __align__(16) u16 Ks[2][64 * 128];   // [channel][key][d]; reused as Bs in phase B
    __shared__ __align__(16) u16 Vt[2][128 * 64];   // [channel][d][key]
    __shared__ __align__(16) u16 PsAo[32 * 256];    // union: Ps during loop / Ao[32][256] after

    int idx = blockIdx.x;
    int qi = (idx < 256) ? (63 - (idx >> 3)) : ((idx - 256) >> 3);  // complementary pairing
    int sub = idx & 7, b = sub >> 1, half = sub & 1;
    int tid = threadIdx.x, lane = tid & 63, w = tid >> 6;
    int ln = lane & 15, quad = lane >> 4;
    int cw = w >> 1, wr = w & 1;       // channel, 16-row tile within the 32-row half
    const float scale = 0.08838834764831845f;  // 1/sqrt(128)

    const unsigned char* mrow = cmask + qi * 64;
    unsigned long long bm = 0;
    for (int k = 0; k <= qi; k++) bm |= (unsigned long long)(mrow[k] != 0) << k;

    const u16* kb_base = qk + (size_t)b * SEQ_L * 512 + 256 + cw * 128;
    const u16* vt_base = vt + (size_t)(b * 2 + cw) * 128 * SEQ_L;

    // Q fragments: A[m=ln][k=32s+8*quad+j]
    bf16x8 qf[4];
    {
        size_t grow = (size_t)(b * SEQ_L + qi * 64 + half * 32 + wr * 16 + ln);
        const u16* qp = qk + grow * 512 + cw * 128;
        #pragma unroll
        for (int s = 0; s < 4; s++) qf[s] = *(const bf16x8*)(qp + 32 * s + 8 * quad);
    }
    float m_st[4], l_st[4];
    #pragma unroll
    for (int r = 0; r < 4; r++) { m_st[r] = -1e30f; l_st[r] = 0.f; }
    f32x4 accO[8] = {};
    u16* Ps = PsAo + w * 1152;   // wave-private 16x72

    while (bm) {
        int cur = __ffsll(bm) - 1; bm &= bm - 1;
        __syncthreads();   // WAR: prior iter's K/V reads done
        {   // stage this wave's channel: K (8 calls x 4 rows), V^T (8 calls x 8 d-rows)
            const u16* kp = kb_base + (size_t)cur * 64 * 512;
            const u16* vp = vt_base + cur * 64;
            #pragma unroll
            for (int j = 0; j < 8; j++) {
                int kr0 = j * 8 + wr * 4, kr = kr0 + (lane >> 4);
                gload16(kp + (size_t)kr * 512 + (((lane & 15) ^ (kr & 7)) * 8),
                        Ks[cw] + kr0 * 128 + lane * 8);
                int d0 = j * 16 + wr * 8, d = d0 + (lane >> 3);
                gload16(vp + (size_t)d * SEQ_L + (((lane & 7) ^ (d & 7)) * 8),
                        Vt[cw] + d0 * 64 + lane * 8);
            }
        }
        __syncthreads();   // drain

        // S = Q K^T : D[m=4*quad+r][n=ln+16t]
        f32x4 accS[4] = {};
        #pragma unroll
        for (int s = 0; s < 4; s++) {
            #pragma unroll
            for (int t = 0; t < 4; t++) {
                int R = t * 16 + ln;
                bf16x8 bfr = *(const bf16x8*)(Ks[cw] + R * 128 + ((4 * s + quad) ^ (ln & 7)) * 8);
                accS[t] = __builtin_amdgcn_mfma_f32_16x16x32_bf16(qf[s], bfr, accS[t], 0, 0, 0);
            }
        }
        // online softmax per row m = 4*quad + r
        float P[4][4];
        #pragma unroll
        for (int r = 0; r < 4; r++) {
            float sv[4];
            float mx = -1e30f;
            #pragma unroll
            for (int t = 0; t < 4; t++) { sv[t] = accS[t][r] * scale; mx = fmaxf(mx, sv[t]); }
            #pragma unroll
            for (int off = 1; off < 16; off <<= 1) mx = fmaxf(mx, __shfl_xor(mx, off, 64));
            float nm = fmaxf(m_st[r], mx);
            float alpha = __expf(m_st[r] - nm);
            m_st[r] = nm;
            float rs = 0.f;
            #pragma unroll
            for (int t = 0; t < 4; t++) { float p = __expf(sv[t] - nm); P[t][r] = p; rs += p; }
            #pragma unroll
            for (int off = 1; off < 16; off <<= 1) rs += __shfl_xor(rs, off, 64);
            l_st[r] = l_st[r] * alpha + rs;
            #pragma unroll
            for (int nt = 0; nt < 8; nt++) accO[nt][r] *= alpha;
        }
        // P: C/D -> A-operand layout via wave-private LDS
        #pragma unroll
        for (int t = 0; t < 4; t++)
            #pragma unroll
            for (int r = 0; r < 4; r++)
                Ps[(4 * quad + r) * 72 + ln + 16 * t] = f2bf(P[t][r]);
        // O += P V
        #pragma unroll
        for (int s2 = 0; s2 < 2; s2++) {
            bf16x8 pf = *(const bf16x8*)(Ps + ln * 72 + 32 * s2 + 8 * quad);
            #pragma unroll
            for (int nt = 0; nt < 8; nt++) {
                int R = nt * 16 + ln;
                bf16x8 vf = *(const bf16x8*)(Vt[cw] + R * 64 + ((4 * s2 + quad) ^ (ln & 7)) * 8);
                accO[nt] = __builtin_amdgcn_mfma_f32_16x16x32_bf16(pf, vf, accO[nt], 0, 0, 0);
            }
        }
    }

    __syncthreads();   // all Ps dead before Ao overwrites the union
    {   // Ao[32][256] <- O / l  (rows wr*16.., cols cw*128..)
        float inv[4];
        #pragma unroll
        for (int r = 0; r < 4; r++) inv[r] = 1.0f / fmaxf(l_st[r], 1e-20f);
        #pragma unroll
        for (int nt = 0; nt < 8; nt++)
            #pragma unroll
            for (int r = 0; r < 4; r++)
                PsAo[(wr * 16 + 4 * quad + r) * 256 + cw * 128 + nt * 16 + ln]
                    = f2bf(accO[nt][r] * inv[r]);
    }

    // -------- phase B: out[32,256] = Ao @ Wout^T + bias, k streamed in 4 chunks --------
    u16* Bs = Ks[0];   // 256 (out cols) x 64 (k) u16 = 32 KB
    f32x4 oacc[2][4] = {};
    for (int kk = 0; kk < 4; kk++) {
        __syncthreads();   // Ao visibility (kk=0) / WAR on Bs
        #pragma unroll
        for (int j = 0; j < 8; j++) {
            int o0 = w * 64 + j * 8, o = o0 + (lane >> 3);
            gload16(Wout + (size_t)o * 256 + kk * 64 + (((lane & 7) ^ (o & 7)) * 8),
                    Bs + o0 * 64 + lane * 8);
        }
        __syncthreads();   // drain
        #pragma unroll
        for (int s = 0; s < 2; s++) {
            bf16x8 af[2], bfr[4];
            #pragma unroll
            for (int i = 0; i < 2; i++)
                af[i] = *(const bf16x8*)(PsAo + (i * 16 + ln) * 256 + kk * 64 + 32 * s + 8 * quad);
            #pragma unroll
            for (int t = 0; t < 4; t++) {
                int o = w * 64 + t * 16 + ln;
                bfr[t] = *(const bf16x8*)(Bs + o * 64 + ((4 * s + quad) ^ (ln & 7)) * 8);
            }
            #pragma unroll
            for (int i = 0; i < 2; i++)
                #pragma unroll
                for (int t = 0; t < 4; t++)
                    oacc[i][t] = __builtin_amdgcn_mfma_f32_16x16x32_bf16(af[i], bfr[t], oacc[i][t], 0, 0, 0);
        }
    }
    const size_t hlf = (size_t)M_TOT * 128;
    #pragma unroll
    for (int t = 0; t < 4; t++) {
        int o = w * 64 + t * 16 + ln;
        float bv = bout[o];
        float* base = (o < 128) ? (out + o) : (out + hlf + (o - 128));
        #pragma unroll
        for (int i = 0; i < 2; i++) {
            int row = b * SEQ_L + qi * 64 + half * 32 + i * 16 + 4 * quad;
            #pragma unroll
            for (int r = 0; r < 4; r++)
                base[(size_t)(row + r) * 128] = oacc[i][t][r] + bv;
        }
    }
}

extern "C" void kernel_launch(void* const* d_in, const int* in_sizes, int n_in,
                              void* d_out, int out_size, void* d_ws, size_t ws_size,
                              hipStream_t stream) {
    char* ws = (char*)d_ws;
    u16* x_bf    = (u16*)ws;                          // 16384*768  = 25.2 MB
    u16* qk_buf  = x_bf + (size_t)M_TOT * 768;        // 16384*512  = 16.8 MB
    u16* vt_buf  = qk_buf + (size_t)M_TOT * 512;      // 1024*4096  =  8.4 MB
    u16* Wqkv_bf = vt_buf + (size_t)1024 * SEQ_L;     // 589824
    u16* Wout_bf = Wqkv_bf + 589824;                  // 65536
    unsigned char* cmask = (unsigned char*)(Wout_bf + 65536);

    hipLaunchKernelGGL(prep_all, dim3(6480), dim3(256), 0, stream,
                       (const float*)d_in[0], (const float*)d_in[1], (const float*)d_in[2],
                       (const float*)d_in[3], (const float*)d_in[4], (const float*)d_in[5],
                       (const float*)d_in[6], (const float*)d_in[8], d_in[10],
                       x_bf, Wqkv_bf, Wout_bf, cmask);
    hipLaunchKernelGGL(qkv_gemm, dim3(128, 12), dim3(256), 0, stream,
                       x_bf, Wqkv_bf, (const float*)d_in[7], qk_buf, vt_buf);
    hipLaunchKernelGGL(attn_out, dim3(512), dim3(256), 0, stream,
                       qk_buf, vt_buf, Wout_bf, cmask, (const float*)d_in[9], (float*)d_out);
}

// Round 11
// 216.663 us; speedup vs baseline: 1.1455x; 1.0107x over previous
//
#include <hip/hip_runtime.h>
#include <hip/hip_bf16.h>

typedef unsigned short u16;
typedef __attribute__((ext_vector_type(8))) short bf16x8;
typedef __attribute__((ext_vector_type(4))) float f32x4;

#define SEQ_L 4096
#define M_TOT 16384   // B*L

__device__ __forceinline__ float bf2f(u16 x) {
    unsigned u = ((unsigned)x) << 16;
    return __builtin_bit_cast(float, u);
}
__device__ __forceinline__ u16 f2bf(float f) {
    unsigned u = __builtin_bit_cast(unsigned, f);
    u += 0x7FFFu + ((u >> 16) & 1u);   // round-to-nearest-even
    return (u16)(u >> 16);
}
// async 16B global->LDS (direct-to-LDS DMA; LDS dest = wave-uniform base + lane*16)
__device__ __forceinline__ void gload16(const u16* g, u16* l) {
    __builtin_amdgcn_global_load_lds(
        (const __attribute__((address_space(1))) unsigned int*)g,
        (__attribute__((address_space(3))) unsigned int*)l, 16, 0, 0);
}

// ---- prep_all: pack six fp32 inputs -> x bf16 | Wqkv,Wout -> bf16 | mask -> u64 bitmap ----
__global__ __launch_bounds__(256) void prep_all(
    const float* __restrict__ in0, const float* __restrict__ in1, const float* __restrict__ in2,
    const float* __restrict__ in3, const float* __restrict__ in4, const float* __restrict__ in5,
    const float* __restrict__ Wqkv, const float* __restrict__ Wout, const void* __restrict__ mask,
    u16* __restrict__ x, u16* __restrict__ Wqkv_bf, u16* __restrict__ Wout_bf,
    unsigned long long* __restrict__ bmap) {
    int id = blockIdx.x * 256 + threadIdx.x;
    if (id < 1572864) {
        const float* ins[6] = {in0, in1, in2, in3, in4, in5};
        int which = id >> 18, j = id & 262143;
        int m = j >> 4, c8 = j & 15;
        const float* sp = ins[which] + (size_t)m * 128 + c8 * 8;
        float4 a = *(const float4*)sp;
        float4 b = *(const float4*)(sp + 4);
        u16 t[8] = {f2bf(a.x), f2bf(a.y), f2bf(a.z), f2bf(a.w),
                    f2bf(b.x), f2bf(b.y), f2bf(b.z), f2bf(b.w)};
        *(uint4*)(x + (size_t)m * 768 + which * 128 + c8 * 8) = *(uint4*)t;
    } else if (id < 1572864 + 73728 + 8192) {
        int i = id - 1572864;
        const float* src = (i < 73728) ? Wqkv : Wout;
        u16* dst = (i < 73728) ? Wqkv_bf : Wout_bf;
        if (i >= 73728) i -= 73728;
        const float* sp = src + (size_t)i * 8;
        float4 a = *(const float4*)sp;
        float4 b = *(const float4*)(sp + 4);
        u16 t[8] = {f2bf(a.x), f2bf(a.y), f2bf(a.z), f2bf(a.w),
                    f2bf(b.x), f2bf(b.y), f2bf(b.z), f2bf(b.w)};
        *(uint4*)(dst + (size_t)i * 8) = *(uint4*)t;
    } else if (id < 1572864 + 73728 + 8192 + 4096) {
        int i = id - 1572864 - 73728 - 8192;   // wave-aligned: one wave = one mask row
        int bi = i >> 6, bj = i & 63;
        size_t e = (size_t)(bi * 64) * SEQ_L + (size_t)bj * 64;
        const unsigned char* p8 = (const unsigned char*)mask;
        unsigned w0 = *(const unsigned*)mask;   // [0][0],[0][1] always true -> fingerprint
        bool v;
        if (w0 == 0x01010101u || w0 == 0xFFFFFFFFu)      v = p8[e] != 0;
        else if (w0 == 0x3F803F80u || w0 == 0x3C003C00u) v = ((const u16*)mask)[e] != 0;
        else                                             v = ((const unsigned*)mask)[e] != 0;
        unsigned long long bits = __ballot(v);
        if ((i & 63) == 0) bmap[bi] = bits;
    }
}

// ---------------- QKV GEMM, 128x64 tile (grid 1536) ----------------
__global__ __launch_bounds__(256, 4) void qkv_gemm(
    const u16* __restrict__ X, const u16* __restrict__ W, const float* __restrict__ bias,
    u16* __restrict__ qk, u16* __restrict__ vt) {
    __shared__ __align__(16) u16 As[128 * 64];
    __shared__ __align__(16) u16 Bs[64 * 64];
    int m0 = blockIdx.x * 128, n0 = blockIdx.y * 64;
    int tid = threadIdx.x, lane = tid & 63, w = tid >> 6;
    int ln = lane & 15, quad = lane >> 4;
    int rw = (w >> 1) * 64, cw = (w & 1) * 32;
    int lr8 = lane >> 3, lc = lane & 7;
    f32x4 acc[4][2] = {};
    for (int kk = 0; kk < 768; kk += 64) {
        __syncthreads();
        #pragma unroll
        for (int j = 0; j < 4; j++) {
            int r0 = w * 32 + j * 8, r = r0 + lr8;
            gload16(X + (size_t)(m0 + r) * 768 + kk + ((lc ^ (r & 7)) * 8), As + r0 * 64 + lane * 8);
        }
        #pragma unroll
        for (int j = 0; j < 2; j++) {
            int r0 = w * 16 + j * 8, r = r0 + lr8;
            gload16(W + (size_t)(n0 + r) * 768 + kk + ((lc ^ (r & 7)) * 8), Bs + r0 * 64 + lane * 8);
        }
        __syncthreads();
        #pragma unroll
        for (int s = 0; s < 2; s++) {
            bf16x8 af[4], bfr[2];
            #pragma unroll
            for (int i = 0; i < 4; i++) {
                int R = rw + i * 16 + ln;
                af[i] = *(const bf16x8*)(As + R * 64 + ((4 * s + quad) ^ (ln & 7)) * 8);
            }
            #pragma unroll
            for (int t = 0; t < 2; t++) {
                int R = cw + t * 16 + ln;
                bfr[t] = *(const bf16x8*)(Bs + R * 64 + ((4 * s + quad) ^ (ln & 7)) * 8);
            }
            #pragma unroll
            for (int i = 0; i < 4; i++)
                #pragma unroll
                for (int t = 0; t < 2; t++)
                    acc[i][t] = __builtin_amdgcn_mfma_f32_16x16x32_bf16(af[i], bfr[t], acc[i][t], 0, 0, 0);
        }
    }
    #pragma unroll
    for (int i = 0; i < 4; i++) {
        int row0 = m0 + rw + i * 16 + 4 * quad;
        #pragma unroll
        for (int t = 0; t < 2; t++) {
            int col = n0 + cw + t * 16 + ln;
            float bv = bias[col];
            if (col < 512) {   // block-uniform (n0 is 64-aligned)
                #pragma unroll
                for (int r = 0; r < 4; r++)
                    qk[(size_t)(row0 + r) * 512 + col] = f2bf(acc[i][t][r] + bv);
            } else {
                int d = col - 512;
                int b = row0 >> 12, seq = row0 & 4095;
                u16 pk[4] = {f2bf(acc[i][t][0] + bv), f2bf(acc[i][t][1] + bv),
                             f2bf(acc[i][t][2] + bv), f2bf(acc[i][t][3] + bv)};
                *(ushort4*)(vt + ((size_t)(b * 2 + (d >> 7)) * 128 + (d & 127)) * SEQ_L + seq)
                    = *(ushort4*)pk;
            }
        }
    }
}

// ---- block-sparse flash attention: fully wave-independent items ----
// Item = (qi, b, channel, 16-row quarter): 2048 waves, 512 blocks x 4 waves.
// Each wave stages K(32x128)+V^T(128x32) subtiles into its PRIVATE LDS slice via
// gload16 and syncs with explicit s_waitcnt vmcnt(N) — no __syncthreads at all.
// vmcnt(8) after staging -> K ready while V still in flight; vmcnt(0) before PV.
__global__ __launch_bounds__(256, 2) void attn_sparse(
    const u16* __restrict__ qk, const u16* __restrict__ vt,
    const unsigned long long* __restrict__ bmap, u16* __restrict__ attn_bf) {
    __shared__ __align__(16) u16 Ksm[4][32 * 128];  // 32 KB
    __shared__ __align__(16) u16 Vsm[4][128 * 32];  // 32 KB
    __shared__ __align__(16) u16 Psm[4][16 * 40];   // 5 KB  (total 69 KB -> 2 blocks/CU)

    int lane = threadIdx.x & 63, w = threadIdx.x >> 6;
    int ln = lane & 15, quad = lane >> 4;
    int g = blockIdx.x * 4 + w;                 // 0..2047
    int u = g >> 5, v = g & 31;
    int qi = (u < 32) ? (63 - u) : (u - 32);    // heavy qi dispatched first
    int b = v >> 3, ch = (v >> 2) & 1, quarter = v & 3;
    int rowbase = b * SEQ_L + qi * 64 + quarter * 16;
    const float scale = 0.08838834764831845f;   // 1/sqrt(128)

    u16* K = Ksm[w];
    u16* V = Vsm[w];
    u16* Ps = Psm[w];

    // Q fragments: A[m=ln][k=32s+8*quad+j]
    bf16x8 qf[4];
    {
        const u16* qp = qk + (size_t)(rowbase + ln) * 512 + ch * 128;
        #pragma unroll
        for (int s = 0; s < 4; s++) qf[s] = *(const bf16x8*)(qp + 32 * s + 8 * quad);
    }
    float m_st[4], l_st[4];
    #pragma unroll
    for (int r = 0; r < 4; r++) { m_st[r] = -1e30f; l_st[r] = 0.f; }
    f32x4 accO[8] = {};

    const u16* kbase0 = qk + (size_t)b * SEQ_L * 512 + 256 + ch * 128;
    const u16* vbase0 = vt + (size_t)(b * 2 + ch) * 128 * SEQ_L;
    unsigned long long bm = bmap[qi];           // tril: bits > qi are already 0

    while (bm) {
        int kb = __ffsll(bm) - 1; bm &= bm - 1;
        #pragma unroll
        for (int sub = 0; sub < 2; sub++) {
            const u16* kp = kbase0 + (size_t)(kb * 64 + sub * 32) * 512;
            const u16* vp = vbase0 + kb * 64 + sub * 32;
            // stage K: 8 calls x 4 key-rows x 16 chunks (xor-swizzled)
            #pragma unroll
            for (int j = 0; j < 8; j++) {
                int kr = j * 4 + (lane >> 4);
                gload16(kp + (size_t)kr * 512 + (((lane & 15) ^ (kr & 7)) * 8),
                        K + j * 4 * 128 + lane * 8);
            }
            // stage V^T: 8 calls x 16 d-rows x 4 chunks (xor-swizzled)
            #pragma unroll
            for (int j = 0; j < 8; j++) {
                int d = j * 16 + (lane >> 2);
                gload16(vp + (size_t)d * SEQ_L + (((lane & 3) ^ (d & 3)) * 8),
                        V + j * 16 * 32 + lane * 8);
            }
            __builtin_amdgcn_s_waitcnt(0x0F78);   // vmcnt(8): K landed, V in flight

            // S = Q K^T over 32 keys: D[m=4*quad+r][n=ln+16t]
            f32x4 accS[2] = {};
            #pragma unroll
            for (int s = 0; s < 4; s++)
                #pragma unroll
                for (int t = 0; t < 2; t++) {
                    bf16x8 kf = *(const bf16x8*)(K + (t * 16 + ln) * 128 +
                                                 (((4 * s + quad) ^ (ln & 7)) * 8));
                    accS[t] = __builtin_amdgcn_mfma_f32_16x16x32_bf16(qf[s], kf, accS[t], 0, 0, 0);
                }

            // online softmax per row m = 4*quad + r
            #pragma unroll
            for (int r = 0; r < 4; r++) {
                float s0 = accS[0][r] * scale, s1 = accS[1][r] * scale;
                float mx = fmaxf(s0, s1);
                #pragma unroll
                for (int off = 1; off < 16; off <<= 1) mx = fmaxf(mx, __shfl_xor(mx, off, 64));
                float nm = fmaxf(m_st[r], mx);
                float alpha = __expf(m_st[r] - nm);
                m_st[r] = nm;
                float p0 = __expf(s0 - nm), p1 = __expf(s1 - nm);
                Ps[(4 * quad + r) * 40 + ln] = f2bf(p0);
                Ps[(4 * quad + r) * 40 + ln + 16] = f2bf(p1);
                float rs = p0 + p1;
                #pragma unroll
                for (int off = 1; off < 16; off <<= 1) rs += __shfl_xor(rs, off, 64);
                l_st[r] = l_st[r] * alpha + rs;
                #pragma unroll
                for (int nt = 0; nt < 8; nt++) accO[nt][r] *= alpha;
            }

            __builtin_amdgcn_s_waitcnt(0x0F70);   // vmcnt(0): V landed
            // O += P V : single K=32 MFMA per 16-col tile
            bf16x8 pf = *(const bf16x8*)(Ps + ln * 40 + 8 * quad);
            #pragma unroll
            for (int nt = 0; nt < 8; nt++) {
                bf16x8 vf = *(const bf16x8*)(V + (nt * 16 + ln) * 32 +
                                             ((quad ^ (ln & 3)) * 8));
                accO[nt] = __builtin_amdgcn_mfma_f32_16x16x32_bf16(pf, vf, accO[nt], 0, 0, 0);
            }
        }
    }

    // epilogue: attn_bf[row][ch*128 + col] = O / l
    float inv[4];
    #pragma unroll
    for (int r = 0; r < 4; r++) inv[r] = 1.0f / fmaxf(l_st[r], 1e-20f);
    #pragma unroll
    for (int nt = 0; nt < 8; nt++)
        #pragma unroll
        for (int r = 0; r < 4; r++)
            attn_bf[(size_t)(rowbase + 4 * quad + r) * 256 + ch * 128 + nt * 16 + ln]
                = f2bf(accO[nt][r] * inv[r]);
}

// ---------------- out projection: attn[16384,256](bf16) @ Wout^T + b -> fp32 halves ----------------
__global__ __launch_bounds__(256) void out_gemm(
    const u16* __restrict__ A, const u16* __restrict__ W, const float* __restrict__ bias,
    float* __restrict__ out) {
    __shared__ __align__(16) u16 As[64 * 64];
    __shared__ __align__(16) u16 Bs[64 * 64];
    int m0 = blockIdx.x * 64, n0 = blockIdx.y * 64;
    int tid = threadIdx.x, lane = tid & 63, w = tid >> 6;
    int ln = lane & 15, quad = lane >> 4;
    int lr8 = lane >> 3, lc = lane & 7;
    int swz_st = lc ^ (lr8 & 7);
    f32x4 acc[4] = {};
    for (int kk = 0; kk < 256; kk += 64) {
        __syncthreads();
        #pragma unroll
        for (int j = 0; j < 2; j++) {
            int r0 = w * 16 + j * 8;
            int r = r0 + lr8;
            gload16(A + (size_t)(m0 + r) * 256 + kk + swz_st * 8, As + r0 * 64 + lane * 8);
            gload16(W + (size_t)(n0 + r) * 256 + kk + swz_st * 8, Bs + r0 * 64 + lane * 8);
        }
        __syncthreads();
        #pragma unroll
        for (int s = 0; s < 2; s++) {
            int R = w * 16 + ln;
            bf16x8 af = *(const bf16x8*)(As + R * 64 + ((4 * s + quad) ^ (ln & 7)) * 8);
            #pragma unroll
            for (int t = 0; t < 4; t++) {
                int Rb = t * 16 + ln;
                bf16x8 bfr = *(const bf16x8*)(Bs + Rb * 64 + ((4 * s + quad) ^ (ln & 7)) * 8);
                acc[t] = __builtin_amdgcn_mfma_f32_16x16x32_bf16(af, bfr, acc[t], 0, 0, 0);
            }
        }
    }
    const size_t half = (size_t)M_TOT * 128;
    #pragma unroll
    for (int t = 0; t < 4; t++) {
        int col = n0 + t * 16 + ln;
        float bv = bias[col];
        float* base = (col < 128) ? (out + col) : (out + half + (col - 128));
        #pragma unroll
        for (int r = 0; r < 4; r++) {
            int row = m0 + w * 16 + 4 * quad + r;
            base[(size_t)row * 128] = acc[t][r] + bv;
        }
    }
}

extern "C" void kernel_launch(void* const* d_in, const int* in_sizes, int n_in,
                              void* d_out, int out_size, void* d_ws, size_t ws_size,
                              hipStream_t stream) {
    char* ws = (char*)d_ws;
    u16* x_bf    = (u16*)ws;                          // 16384*768  = 25.2 MB
    u16* qk_buf  = x_bf + (size_t)M_TOT * 768;        // 16384*512  = 16.8 MB
    u16* vt_buf  = qk_buf + (size_t)M_TOT * 512;      // 1024*4096  =  8.4 MB
    u16* attn_bf = vt_buf + (size_t)1024 * SEQ_L;     // 16384*256  =  8.4 MB
    u16* Wqkv_bf = attn_bf + (size_t)M_TOT * 256;     // 589824
    u16* Wout_bf = Wqkv_bf + 589824;                  // 65536
    unsigned long long* bmap = (unsigned long long*)(Wout_bf + 65536);   // 64 x u64

    hipLaunchKernelGGL(prep_all, dim3(6480), dim3(256), 0, stream,
                       (const float*)d_in[0], (const float*)d_in[1], (const float*)d_in[2],
                       (const float*)d_in[3], (const float*)d_in[4], (const float*)d_in[5],
                       (const float*)d_in[6], (const float*)d_in[8], d_in[10],
                       x_bf, Wqkv_bf, Wout_bf, bmap);
    hipLaunchKernelGGL(qkv_gemm, dim3(128, 12), dim3(256), 0, stream,
                       x_bf, Wqkv_bf, (const float*)d_in[7], qk_buf, vt_buf);
    hipLaunchKernelGGL(attn_sparse, dim3(512), dim3(256), 0, stream,
                       qk_buf, vt_buf, bmap, attn_bf);
    hipLaunchKernelGGL(out_gemm, dim3(256, 4), dim3(256), 0, stream,
                       attn_bf, Wout_bf, (const float*)d_in[9], (float*)d_out);
}